// Round 1
// baseline (193.498 us; speedup 1.0000x reference)
//
#include <hip/hip_runtime.h>
#include <hip/hip_bf16.h>

#define B_      8
#define S_      1024
#define H_      16
#define DH      64
#define UNITS_  1024
#define MSTRIDE 2048
#define KVB     64
#define QTB     64
#define LP      72   // LDS row pad: 64 + 8 bf16 -> 144B row stride, 16B aligned

typedef __attribute__((ext_vector_type(8))) short bf16x8;
typedef __attribute__((ext_vector_type(4))) float f32x4;

__device__ __forceinline__ unsigned short f2bf(float f) {
    union { float f; unsigned u; } x; x.f = f;
    unsigned r = x.u + 0x7fffu + ((x.u >> 16) & 1u);
    return (unsigned short)(r >> 16);
}

__global__ __launch_bounds__(256)
void attn_kernel(const float* __restrict__ mem, const float* __restrict__ qry,
                 const float* __restrict__ bias, const int* __restrict__ slen,
                 float* __restrict__ out)
{
    __shared__ alignas(16) unsigned short Qs[QTB][LP];
    __shared__ alignas(16) unsigned short Ks[KVB][LP];
    __shared__ alignas(16) unsigned short Vt[DH][LP];   // V transposed: [dh][key]
    __shared__ alignas(16) unsigned short Ps[4][16][LP];

    const int tid  = threadIdx.x;
    const int wq   = tid >> 6;      // wave id 0..3 -> q rows [wq*16, wq*16+16)
    const int lane = tid & 63;
    const int lr   = lane & 15;
    const int lg   = lane >> 4;

    const int qt = blockIdx.x;
    const int h  = blockIdx.y;
    const int b  = blockIdx.z;

    int L = slen[b];
    if (L == 0) L = S_;             // all-masked => softmax shift-invariance => full attn
    const int ntiles = (L + KVB - 1) / KVB;

    const float* qp = qry + ((size_t)(b * S_ + qt * QTB)) * UNITS_ + h * DH;
    const float* kp = mem + ((size_t)b * S_) * MSTRIDE + h * DH;
    const float* vp = kp + UNITS_;
    float*       op = out + ((size_t)(b * S_ + qt * QTB)) * UNITS_ + h * DH;

    // ---- stage Q (pre-scaled by dh^-0.5) ----
    {
        const int row = tid >> 2;
        const int cb  = (tid & 3) * 16;
        const float4* src = (const float4*)(qp + (size_t)row * UNITS_ + cb);
        union { unsigned short us[16]; uint4 v[2]; } t;
        #pragma unroll
        for (int i = 0; i < 4; ++i) {
            float4 f = src[i];
            t.us[i*4+0] = f2bf(f.x * 0.125f);
            t.us[i*4+1] = f2bf(f.y * 0.125f);
            t.us[i*4+2] = f2bf(f.z * 0.125f);
            t.us[i*4+3] = f2bf(f.w * 0.125f);
        }
        uint4* d = (uint4*)&Qs[row][cb];
        d[0] = t.v[0]; d[1] = t.v[1];
    }
    __syncthreads();

    bf16x8 qf[2];
    #pragma unroll
    for (int kc = 0; kc < 2; ++kc)
        qf[kc] = *(const bf16x8*)&Qs[wq*16 + lr][kc*32 + lg*8];

    f32x4 o[4];
    float m[4], ls[4];
    #pragma unroll
    for (int r = 0; r < 4; ++r) {
        o[r] = (f32x4){0.f,0.f,0.f,0.f};
        m[r] = -INFINITY; ls[r] = 0.f;
    }

    for (int t = 0; t < ntiles; ++t) {
        const int kvb = t * KVB;
        // ---- stage K row-major, V transposed ----
        {
            const int row = tid >> 2;
            const int cb  = (tid & 3) * 16;
            const float4* ks = (const float4*)(kp + (size_t)(kvb + row) * MSTRIDE + cb);
            union { unsigned short us[16]; uint4 v[2]; } tk;
            #pragma unroll
            for (int i = 0; i < 4; ++i) {
                float4 f = ks[i];
                tk.us[i*4+0] = f2bf(f.x); tk.us[i*4+1] = f2bf(f.y);
                tk.us[i*4+2] = f2bf(f.z); tk.us[i*4+3] = f2bf(f.w);
            }
            uint4* d = (uint4*)&Ks[row][cb];
            d[0] = tk.v[0]; d[1] = tk.v[1];
            const float4* vs = (const float4*)(vp + (size_t)(kvb + row) * MSTRIDE + cb);
            #pragma unroll
            for (int i = 0; i < 4; ++i) {
                float4 f = vs[i];
                Vt[cb + i*4 + 0][row] = f2bf(f.x);
                Vt[cb + i*4 + 1][row] = f2bf(f.y);
                Vt[cb + i*4 + 2][row] = f2bf(f.z);
                Vt[cb + i*4 + 3][row] = f2bf(f.w);
            }
        }
        __syncthreads();

        // ---- QK^T: S[16 x 64] per wave ----
        f32x4 s[4];
        #pragma unroll
        for (int cb = 0; cb < 4; ++cb) {
            f32x4 acc = (f32x4){0.f,0.f,0.f,0.f};
            #pragma unroll
            for (int kc = 0; kc < 2; ++kc) {
                bf16x8 kf = *(const bf16x8*)&Ks[cb*16 + lr][kc*32 + lg*8];
                acc = __builtin_amdgcn_mfma_f32_16x16x32_bf16(qf[kc], kf, acc, 0, 0, 0);
            }
            s[cb] = acc;
        }

        // ---- bias + mask + online softmax ----
        float p[4][4];
        float rowm[4] = {-INFINITY, -INFINITY, -INFINITY, -INFINITY};
        #pragma unroll
        for (int cb = 0; cb < 4; ++cb) {
            const int key = kvb + cb*16 + lr;
            const float bb = bias[key];
            const bool valid = key < L;
            #pragma unroll
            for (int r = 0; r < 4; ++r) {
                float v = valid ? (s[cb][r] + bb) : -INFINITY;
                p[cb][r] = v;
                rowm[r] = fmaxf(rowm[r], v);
            }
        }
        #pragma unroll
        for (int off = 1; off < 16; off <<= 1) {
            #pragma unroll
            for (int r = 0; r < 4; ++r)
                rowm[r] = fmaxf(rowm[r], __shfl_xor(rowm[r], off, 64));
        }
        float sc[4], rs[4];
        #pragma unroll
        for (int r = 0; r < 4; ++r) {
            float mnew = fmaxf(m[r], rowm[r]);
            sc[r] = __expf(m[r] - mnew);   // m=-inf on first tile -> 0
            m[r] = mnew;
            float acc = 0.f;
            #pragma unroll
            for (int cb = 0; cb < 4; ++cb) {
                float e = __expf(p[cb][r] - mnew);   // masked(-inf) -> 0
                p[cb][r] = e;
                acc += e;
            }
            rs[r] = acc;
        }
        #pragma unroll
        for (int off = 1; off < 16; off <<= 1) {
            #pragma unroll
            for (int r = 0; r < 4; ++r)
                rs[r] += __shfl_xor(rs[r], off, 64);
        }
        #pragma unroll
        for (int r = 0; r < 4; ++r) {
            ls[r] = ls[r] * sc[r] + rs[r];
            #pragma unroll
            for (int c = 0; c < 4; ++c)
                o[c][r] *= sc[r];
        }

        // ---- P -> LDS (per-wave transpose buffer) ----
        #pragma unroll
        for (int cb = 0; cb < 4; ++cb)
            #pragma unroll
            for (int r = 0; r < 4; ++r)
                Ps[wq][lg*4 + r][cb*16 + lr] = f2bf(p[cb][r]);
        asm volatile("s_waitcnt lgkmcnt(0)" ::: "memory");  // cross-lane LDS write->read in same wave

        // ---- PV ----
        #pragma unroll
        for (int kc = 0; kc < 2; ++kc) {
            bf16x8 pf = *(const bf16x8*)&Ps[wq][lr][kc*32 + lg*8];
            #pragma unroll
            for (int c = 0; c < 4; ++c) {
                bf16x8 vf = *(const bf16x8*)&Vt[c*16 + lr][kc*32 + lg*8];
                o[c] = __builtin_amdgcn_mfma_f32_16x16x32_bf16(pf, vf, o[c], 0, 0, 0);
            }
        }
        __syncthreads();
    }

    // ---- normalize + store ----
    #pragma unroll
    for (int r = 0; r < 4; ++r) {
        const float inv = 1.0f / ls[r];
        float* orow = op + (size_t)(wq*16 + lg*4 + r) * UNITS_;
        #pragma unroll
        for (int c = 0; c < 4; ++c)
            orow[c*16 + lr] = o[c][r] * inv;
    }
}

extern "C" void kernel_launch(void* const* d_in, const int* in_sizes, int n_in,
                              void* d_out, int out_size, void* d_ws, size_t ws_size,
                              hipStream_t stream) {
    const float* mem  = (const float*)d_in[0];
    const float* qry  = (const float*)d_in[1];
    const float* bias = (const float*)d_in[2];
    const int*   slen = (const int*)d_in[3];
    float*       out  = (float*)d_out;
    dim3 grid(S_ / QTB, H_, B_);
    attn_kernel<<<grid, dim3(256), 0, stream>>>(mem, qry, bias, slen, out);
}